// Round 4
// baseline (354.215 us; speedup 1.0000x reference)
//
#include <hip/hip_runtime.h>
#include <stdint.h>

#define N_VOX   (1 << 19)
#define CIN     64
#define COUT    128
#define BIN_SHIFT 6
#define BINS    (1 << 17)
#define EPSV    1e-5f

// d_out: out_f [N,128] f32, then new_idx [N,4] as f32.
// Only ~25% of rows (y%2==0 && x%2==0, i.e. (lin & 0x201)==0) need GEMM+LN;
// the rest get zeros + (-1,-1,-1,-1). Sort: hist over lin>>6 bins + scan +
// scatter (packed lin<<9|off, no 2nd atomic) + insertion-sort fixup for
// stability on duplicate lin (key = lin<<19 | j, matching stable argsort).
//
// ws ints: hist[BINS] | vcount | pad3 | cursor[BINS] | packed[N] | perm[N]
//          | vlist[N] | partials[128]   (~7.3 MB)

__global__ void k_hist(const int* __restrict__ idx, unsigned* __restrict__ packed,
                       int* __restrict__ hist) {
    int j = blockIdx.x * 256 + threadIdx.x;
    int4 v = *(const int4*)&idx[j * 4];
    int lin = ((v.x * 8 + v.y) * 512 + v.z) * 512 + v.w;
    int off = atomicAdd(&hist[lin >> BIN_SHIFT], 1);
    packed[j] = ((unsigned)lin << 9) | (unsigned)off;   // off < 512 (Poisson λ=4)
}

__global__ void scan_partial(const int* __restrict__ hist, int* __restrict__ partials) {
    __shared__ int sdata[256];
    int base = blockIdx.x * 1024;
    int t = threadIdx.x;
    int s = hist[base + t] + hist[base + t + 256] + hist[base + t + 512] + hist[base + t + 768];
    sdata[t] = s;
    __syncthreads();
    for (int off = 128; off > 0; off >>= 1) {
        if (t < off) sdata[t] += sdata[t + off];
        __syncthreads();
    }
    if (t == 0) partials[blockIdx.x] = sdata[0];
}

__global__ void scan_top(int* __restrict__ partials) {
    __shared__ int sdata[128];
    int t = threadIdx.x;
    sdata[t] = partials[t];
    __syncthreads();
    for (int off = 1; off < 128; off <<= 1) {
        int v = 0;
        if (t >= off) v = sdata[t - off];
        __syncthreads();
        sdata[t] += v;
        __syncthreads();
    }
    partials[t] = t ? sdata[t - 1] : 0;
}

__global__ void scan_final(const int* __restrict__ hist, const int* __restrict__ partials,
                           int* __restrict__ cursor) {
    __shared__ int sscan[256];
    int t = threadIdx.x;
    int base = blockIdx.x * 1024 + t * 4;
    int4 v = *(const int4*)&hist[base];
    int s0 = v.x, s1 = v.x + v.y, s2 = s1 + v.z, s3 = s2 + v.w;
    sscan[t] = s3;
    __syncthreads();
    for (int off = 1; off < 256; off <<= 1) {
        int u = 0;
        if (t >= off) u = sscan[t - off];
        __syncthreads();
        sscan[t] += u;
        __syncthreads();
    }
    int prefix = partials[blockIdx.x] + (t ? sscan[t - 1] : 0);
    int4 e;
    e.x = prefix;
    e.y = prefix + s0;
    e.z = prefix + s1;
    e.w = prefix + s2;
    *(int4*)&cursor[base] = e;   // cursor = bin start, never modified after
}

__global__ void k_scatter(const unsigned* __restrict__ packed, const int* __restrict__ cursor,
                          int* __restrict__ perm) {
    int j = blockIdx.x * 256 + threadIdx.x;
    unsigned p = packed[j];
    int pos = cursor[p >> (9 + BIN_SHIFT)] + (int)(p & 0x1FFu);
    perm[pos] = j;
}

__global__ void k_fixup(const int* __restrict__ hist, const int* __restrict__ cursor,
                        const unsigned* __restrict__ packed, int* __restrict__ perm) {
    int b = blockIdx.x * 256 + threadIdx.x;
    int c = hist[b];
    if (c < 2) return;
    int s = cursor[b];
    for (int i = 1; i < c; i++) {
        int pj = perm[s + i];
        unsigned long long kj =
            ((unsigned long long)(packed[pj] >> 9) << 19) | (unsigned)pj;
        int m = i - 1;
        while (m >= 0) {
            int pm = perm[s + m];
            unsigned long long km =
                ((unsigned long long)(packed[pm] >> 9) << 19) | (unsigned)pm;
            if (km <= kj) break;
            perm[s + m + 1] = pm;
            m--;
        }
        perm[s + m + 1] = pj;
    }
}

// zeros + new_idx=-1 for invalid rows; builds vlist of valid positions.
__global__ __launch_bounds__(256) void k_finalize(
    const int* __restrict__ perm, const unsigned* __restrict__ packed,
    int* __restrict__ vlist, int* __restrict__ vcount, float* __restrict__ out) {
    int tid = threadIdx.x;
    int w = tid >> 6, lane = tid & 63;
    int r0 = blockIdx.x * 128 + w * 32;
    int r = r0 + (lane & 31);
    bool lt32 = lane < 32;
    bool valid = false, inval = false;
    if (lt32) {
        int j = perm[r];
        unsigned lin = packed[j] >> 9;
        valid = ((lin & 0x201u) == 0u);
        inval = !valid;
    }
    if (lt32 && inval) {
        float4 mi = make_float4(-1.f, -1.f, -1.f, -1.f);
        *(float4*)&out[(size_t)N_VOX * COUT + (size_t)r * 4] = mi;
    }
    unsigned long long bv = __ballot(valid);
    if (bv) {
        int cnt = __builtin_popcountll(bv);
        int leader = __builtin_ctzll(bv);
        int base = 0;
        if (lane == leader) base = atomicAdd(vcount, cnt);
        base = __shfl(base, leader);
        if (valid) {
            int myoff = __builtin_popcountll(bv & ((1ull << lane) - 1ull));
            vlist[base + myoff] = r;
        }
    }
    unsigned long long bi = __ballot(inval);
    float4 z = make_float4(0.f, 0.f, 0.f, 0.f);
    // two rows per iteration: lanes 0-31 row l, lanes 32-63 row l+1
    #pragma unroll
    for (int l = 0; l < 32; l += 2) {
        int lr = l + (lane >> 5);
        if ((bi >> lr) & 1ull) {
            *(float4*)&out[(size_t)(r0 + lr) * COUT + (lane & 31) * 4] = z;
        }
    }
}

// GEMM + LN for valid rows only. 512 thr, 8 waves x 16 rows = 128 rows/block.
__global__ __launch_bounds__(512) void k_valid(
    const float* __restrict__ feats, const float* __restrict__ weight,
    const float* __restrict__ gamma, const float* __restrict__ beta,
    const int* __restrict__ perm, const unsigned* __restrict__ packed,
    const int* __restrict__ vlist, const int* __restrict__ vcount,
    float* __restrict__ out) {
    __shared__ float Wlds[CIN][COUT];       // 32 KB
    __shared__ float featb[8][16][CIN];     // 32 KB (wave-private slices)
    int tid = threadIdx.x;
    int vc = *vcount;
    if ((int)blockIdx.x * 128 >= vc) return;

    #pragma unroll
    for (int i = 0; i < 4; i++) {
        int e = tid + i * 512;
        *(float4*)&((float*)Wlds)[e * 4] = *(const float4*)&weight[e * 4];
    }
    __syncthreads();

    int w = tid >> 6, lane = tid & 63;
    float2 gv = *(const float2*)&gamma[lane * 2];
    float2 bvv = *(const float2*)&beta[lane * 2];

    for (int mb = blockIdx.x * 128; mb < vc; mb += gridDim.x * 128) {
        int mrow = mb + w * 16;
        // stage 16 rows (wave-private LDS slice; no block barrier needed)
        #pragma unroll
        for (int i = 0; i < 16; i++) {
            int m = mrow + i;
            int pos = (m < vc) ? vlist[m] : vlist[mb];
            int j = perm[pos];
            featb[w][i][lane] = feats[(size_t)j * CIN + lane];
        }

        float2 acc[16];
        #pragma unroll
        for (int i = 0; i < 16; i++) { acc[i].x = 0.f; acc[i].y = 0.f; }

        #pragma unroll 4
        for (int k0 = 0; k0 < CIN; k0 += 4) {
            float2 wv0 = *(float2*)&Wlds[k0 + 0][lane * 2];
            float2 wv1 = *(float2*)&Wlds[k0 + 1][lane * 2];
            float2 wv2 = *(float2*)&Wlds[k0 + 2][lane * 2];
            float2 wv3 = *(float2*)&Wlds[k0 + 3][lane * 2];
            #pragma unroll
            for (int i = 0; i < 16; i++) {
                float4 f = *(float4*)&featb[w][i][k0];
                acc[i].x = fmaf(f.x, wv0.x, acc[i].x); acc[i].y = fmaf(f.x, wv0.y, acc[i].y);
                acc[i].x = fmaf(f.y, wv1.x, acc[i].x); acc[i].y = fmaf(f.y, wv1.y, acc[i].y);
                acc[i].x = fmaf(f.z, wv2.x, acc[i].x); acc[i].y = fmaf(f.z, wv2.y, acc[i].y);
                acc[i].x = fmaf(f.w, wv3.x, acc[i].x); acc[i].y = fmaf(f.w, wv3.y, acc[i].y);
            }
        }

        #pragma unroll
        for (int i = 0; i < 16; i++) {
            int m = mrow + i;
            float v0 = acc[i].x, v1 = acc[i].y;
            float s = v0 + v1;
            float sq = v0 * v0 + v1 * v1;
            #pragma unroll
            for (int off = 32; off > 0; off >>= 1) {
                s  += __shfl_xor(s, off);
                sq += __shfl_xor(sq, off);
            }
            float mean = s * (1.0f / COUT);
            float var  = fmaxf(sq * (1.0f / COUT) - mean * mean, 0.0f);
            float rstd = rsqrtf(var + EPSV);
            if (m < vc) {                       // wave-uniform
                int pos = vlist[m];
                int j = perm[pos];
                unsigned lin = packed[j] >> 9;
                float2 o;
                o.x = (v0 - mean) * rstd * gv.x + bvv.x;
                o.y = (v1 - mean) * rstd * gv.y + bvv.y;
                *(float2*)&out[(size_t)pos * COUT + lane * 2] = o;
                if (lane == 0) {
                    float4 ni;
                    ni.x = (float)(lin >> 21);
                    ni.y = (float)((lin >> 18) & 7u);
                    ni.z = (float)(((lin >> 9) & 511u) >> 1);
                    ni.w = (float)((lin & 511u) >> 1);
                    *(float4*)&out[(size_t)N_VOX * COUT + (size_t)pos * 4] = ni;
                }
            }
        }
    }
}

extern "C" void kernel_launch(void* const* d_in, const int* in_sizes, int n_in,
                              void* d_out, int out_size, void* d_ws, size_t ws_size,
                              hipStream_t stream) {
    const float* feats  = (const float*)d_in[0];
    const int*   idx    = (const int*)d_in[1];
    const float* weight = (const float*)d_in[2];
    const float* gamma  = (const float*)d_in[3];
    const float* beta   = (const float*)d_in[4];
    float* out = (float*)d_out;

    int* ws = (int*)d_ws;
    int*      hist     = ws;                            // BINS
    int*      vcount   = ws + BINS;                     // 1 (+3 pad)
    int*      cursor   = ws + BINS + 4;                 // BINS
    unsigned* packed   = (unsigned*)(ws + 2 * BINS + 4);// N
    int*      perm     = ws + 2 * BINS + 4 + N_VOX;     // N
    int*      vlist    = ws + 2 * BINS + 4 + 2 * N_VOX; // N
    int*      partials = ws + 2 * BINS + 4 + 3 * N_VOX; // 128

    hipMemsetAsync(hist, 0, (BINS + 4) * sizeof(int), stream);  // hist + vcount
    k_hist<<<N_VOX / 256, 256, 0, stream>>>(idx, packed, hist);
    scan_partial<<<BINS / 1024, 256, 0, stream>>>(hist, partials);
    scan_top<<<1, 128, 0, stream>>>(partials);
    scan_final<<<BINS / 1024, 256, 0, stream>>>(hist, partials, cursor);
    k_scatter<<<N_VOX / 256, 256, 0, stream>>>(packed, cursor, perm);
    k_fixup<<<BINS / 256, 256, 0, stream>>>(hist, cursor, packed, perm);
    k_finalize<<<N_VOX / 128, 256, 0, stream>>>(perm, packed, vlist, vcount, out);
    k_valid<<<2048, 512, 0, stream>>>(feats, weight, gamma, beta,
                                      perm, packed, vlist, vcount, out);
}

// Round 5
// 222.937 us; speedup vs baseline: 1.5889x; 1.5889x over previous
//
#include <hip/hip_runtime.h>
#include <stdint.h>

#define N_VOX   (1 << 19)
#define CIN     64
#define COUT    128
#define BIN_SHIFT 6
#define BINS    (1 << 17)
#define EPSV    1e-5f

typedef float f32x4 __attribute__((ext_vector_type(4)));
typedef float f32x2 __attribute__((ext_vector_type(2)));

static __device__ __forceinline__ void nt_store4(float* p, f32x4 v) {
    __builtin_nontemporal_store(v, (f32x4*)p);
}
static __device__ __forceinline__ void nt_store2(float* p, f32x2 v) {
    __builtin_nontemporal_store(v, (f32x2*)p);
}

// d_out: out_f [N,128] f32, then new_idx [N,4] f32.
// valid row <=> (lin & 0x201)==0 (y%2==0 && x%2==0).
// ws ints: hist[BINS] | vcount(+3) | cursor[BINS] | packed[N] | perm[N]
//          | vlist[N] | partials[128]

__global__ void k_hist(const int* __restrict__ idx, unsigned* __restrict__ packed,
                       int* __restrict__ hist) {
    int j = blockIdx.x * 256 + threadIdx.x;
    int4 v = *(const int4*)&idx[j * 4];
    int lin = ((v.x * 8 + v.y) * 512 + v.z) * 512 + v.w;
    int off = atomicAdd(&hist[lin >> BIN_SHIFT], 1);
    packed[j] = ((unsigned)lin << 9) | (unsigned)off;   // off < 512 (Poisson λ=4)
}

__global__ void scan_partial(const int* __restrict__ hist, int* __restrict__ partials) {
    __shared__ int sdata[256];
    int base = blockIdx.x * 1024;
    int t = threadIdx.x;
    int s = hist[base + t] + hist[base + t + 256] + hist[base + t + 512] + hist[base + t + 768];
    sdata[t] = s;
    __syncthreads();
    for (int off = 128; off > 0; off >>= 1) {
        if (t < off) sdata[t] += sdata[t + off];
        __syncthreads();
    }
    if (t == 0) partials[blockIdx.x] = sdata[0];
}

__global__ void scan_top(int* __restrict__ partials) {
    __shared__ int sdata[128];
    int t = threadIdx.x;
    sdata[t] = partials[t];
    __syncthreads();
    for (int off = 1; off < 128; off <<= 1) {
        int v = 0;
        if (t >= off) v = sdata[t - off];
        __syncthreads();
        sdata[t] += v;
        __syncthreads();
    }
    partials[t] = t ? sdata[t - 1] : 0;
}

__global__ void scan_final(const int* __restrict__ hist, const int* __restrict__ partials,
                           int* __restrict__ cursor) {
    __shared__ int sscan[256];
    int t = threadIdx.x;
    int base = blockIdx.x * 1024 + t * 4;
    int4 v = *(const int4*)&hist[base];
    int s0 = v.x, s1 = v.x + v.y, s2 = s1 + v.z, s3 = s2 + v.w;
    sscan[t] = s3;
    __syncthreads();
    for (int off = 1; off < 256; off <<= 1) {
        int u = 0;
        if (t >= off) u = sscan[t - off];
        __syncthreads();
        sscan[t] += u;
        __syncthreads();
    }
    int prefix = partials[blockIdx.x] + (t ? sscan[t - 1] : 0);
    int4 e;
    e.x = prefix;
    e.y = prefix + s0;
    e.z = prefix + s1;
    e.w = prefix + s2;
    *(int4*)&cursor[base] = e;   // cursor = bin start, never modified after
}

__global__ void k_scatter(const unsigned* __restrict__ packed, const int* __restrict__ cursor,
                          int* __restrict__ perm) {
    int j = blockIdx.x * 256 + threadIdx.x;
    unsigned p = packed[j];
    int pos = cursor[p >> (9 + BIN_SHIFT)] + (int)(p & 0x1FFu);
    perm[pos] = j;
}

__global__ void k_fixup(const int* __restrict__ hist, const int* __restrict__ cursor,
                        const unsigned* __restrict__ packed, int* __restrict__ perm) {
    int b = blockIdx.x * 256 + threadIdx.x;
    int c = hist[b];
    if (c < 2) return;
    int s = cursor[b];
    for (int i = 1; i < c; i++) {
        int pj = perm[s + i];
        unsigned long long kj =
            ((unsigned long long)(packed[pj] >> 9) << 19) | (unsigned)pj;
        int m = i - 1;
        while (m >= 0) {
            int pm = perm[s + m];
            unsigned long long km =
                ((unsigned long long)(packed[pm] >> 9) << 19) | (unsigned)pm;
            if (km <= kj) break;
            perm[s + m + 1] = pm;
            m--;
        }
        perm[s + m + 1] = pj;
    }
}

// zeros + new_idx=-1 for invalid rows (nt stores); builds vlist of valid
// positions with ONE vcount atomic per block.
__global__ __launch_bounds__(256) void k_finalize(
    const int* __restrict__ perm, const unsigned* __restrict__ packed,
    int* __restrict__ vlist, int* __restrict__ vcount, float* __restrict__ out) {
    __shared__ int swoff[4];
    __shared__ int sbase;
    int tid = threadIdx.x;
    int w = tid >> 6, lane = tid & 63;
    int r0 = blockIdx.x * 128 + w * 32;
    int r = r0 + (lane & 31);
    bool lt32 = lane < 32;
    bool valid = false, inval = false;
    if (lt32) {
        int j = perm[r];
        unsigned lin = packed[j] >> 9;
        valid = ((lin & 0x201u) == 0u);
        inval = !valid;
    }
    unsigned long long bv = __ballot(valid);   // bits 0..31 only
    if (lane == 0) swoff[w] = __builtin_popcountll(bv);
    __syncthreads();
    if (tid == 0) {
        int c0 = swoff[0], c1 = swoff[1], c2 = swoff[2], c3 = swoff[3];
        sbase = atomicAdd(vcount, c0 + c1 + c2 + c3);
        swoff[0] = 0; swoff[1] = c0; swoff[2] = c0 + c1; swoff[3] = c0 + c1 + c2;
    }
    __syncthreads();
    if (valid) {
        int myoff = __builtin_popcountll(bv & ((1ull << lane) - 1ull));
        vlist[sbase + swoff[w] + myoff] = r;
    }
    if (lt32 && inval) {
        f32x4 mi = {-1.f, -1.f, -1.f, -1.f};
        nt_store4(&out[(size_t)N_VOX * COUT + (size_t)r * 4], mi);
    }
    unsigned long long bi = __ballot(inval);
    f32x4 z = {0.f, 0.f, 0.f, 0.f};
    // two rows per iteration: lanes 0-31 row l, lanes 32-63 row l+1
    #pragma unroll
    for (int l = 0; l < 32; l += 2) {
        int lr = l + (lane >> 5);
        if ((bi >> lr) & 1ull) {
            nt_store4(&out[(size_t)(r0 + lr) * COUT + (lane & 31) * 4], z);
        }
    }
}

// GEMM + LN for valid rows only. 512 thr, 8 waves x 16 rows = 128 rows/block.
__global__ __launch_bounds__(512) void k_valid(
    const float* __restrict__ feats, const float* __restrict__ weight,
    const float* __restrict__ gamma, const float* __restrict__ beta,
    const int* __restrict__ perm, const unsigned* __restrict__ packed,
    const int* __restrict__ vlist, const int* __restrict__ vcount,
    float* __restrict__ out) {
    __shared__ float Wlds[CIN][COUT];       // 32 KB
    __shared__ float featb[8][16][CIN];     // 32 KB (wave-private slices)
    int tid = threadIdx.x;
    int vc = *vcount;
    if ((int)blockIdx.x * 128 >= vc) return;

    #pragma unroll
    for (int i = 0; i < 4; i++) {
        int e = tid + i * 512;
        *(float4*)&((float*)Wlds)[e * 4] = *(const float4*)&weight[e * 4];
    }
    __syncthreads();

    int w = tid >> 6, lane = tid & 63;
    float2 gv = *(const float2*)&gamma[lane * 2];
    float2 bvv = *(const float2*)&beta[lane * 2];

    for (int mb = blockIdx.x * 128; mb < vc; mb += gridDim.x * 128) {
        int mrow = mb + w * 16;
        #pragma unroll
        for (int i = 0; i < 16; i++) {
            int m = mrow + i;
            int pos = (m < vc) ? vlist[m] : vlist[mb];
            int j = perm[pos];
            featb[w][i][lane] = feats[(size_t)j * CIN + lane];
        }

        float2 acc[16];
        #pragma unroll
        for (int i = 0; i < 16; i++) { acc[i].x = 0.f; acc[i].y = 0.f; }

        #pragma unroll 4
        for (int k0 = 0; k0 < CIN; k0 += 4) {
            float2 wv0 = *(float2*)&Wlds[k0 + 0][lane * 2];
            float2 wv1 = *(float2*)&Wlds[k0 + 1][lane * 2];
            float2 wv2 = *(float2*)&Wlds[k0 + 2][lane * 2];
            float2 wv3 = *(float2*)&Wlds[k0 + 3][lane * 2];
            #pragma unroll
            for (int i = 0; i < 16; i++) {
                float4 f = *(float4*)&featb[w][i][k0];
                acc[i].x = fmaf(f.x, wv0.x, acc[i].x); acc[i].y = fmaf(f.x, wv0.y, acc[i].y);
                acc[i].x = fmaf(f.y, wv1.x, acc[i].x); acc[i].y = fmaf(f.y, wv1.y, acc[i].y);
                acc[i].x = fmaf(f.z, wv2.x, acc[i].x); acc[i].y = fmaf(f.z, wv2.y, acc[i].y);
                acc[i].x = fmaf(f.w, wv3.x, acc[i].x); acc[i].y = fmaf(f.w, wv3.y, acc[i].y);
            }
        }

        #pragma unroll
        for (int i = 0; i < 16; i++) {
            int m = mrow + i;
            float v0 = acc[i].x, v1 = acc[i].y;
            float s = v0 + v1;
            float sq = v0 * v0 + v1 * v1;
            #pragma unroll
            for (int off = 32; off > 0; off >>= 1) {
                s  += __shfl_xor(s, off);
                sq += __shfl_xor(sq, off);
            }
            float mean = s * (1.0f / COUT);
            float var  = fmaxf(sq * (1.0f / COUT) - mean * mean, 0.0f);
            float rstd = rsqrtf(var + EPSV);
            if (m < vc) {                       // wave-uniform
                int pos = vlist[m];
                int j = perm[pos];
                unsigned lin = packed[j] >> 9;
                f32x2 o;
                o.x = (v0 - mean) * rstd * gv.x + bvv.x;
                o.y = (v1 - mean) * rstd * gv.y + bvv.y;
                nt_store2(&out[(size_t)pos * COUT + lane * 2], o);
                if (lane == 0) {
                    f32x4 ni;
                    ni.x = (float)(lin >> 21);
                    ni.y = (float)((lin >> 18) & 7u);
                    ni.z = (float)(((lin >> 9) & 511u) >> 1);
                    ni.w = (float)((lin & 511u) >> 1);
                    nt_store4(&out[(size_t)N_VOX * COUT + (size_t)pos * 4], ni);
                }
            }
        }
    }
}

extern "C" void kernel_launch(void* const* d_in, const int* in_sizes, int n_in,
                              void* d_out, int out_size, void* d_ws, size_t ws_size,
                              hipStream_t stream) {
    const float* feats  = (const float*)d_in[0];
    const int*   idx    = (const int*)d_in[1];
    const float* weight = (const float*)d_in[2];
    const float* gamma  = (const float*)d_in[3];
    const float* beta   = (const float*)d_in[4];
    float* out = (float*)d_out;

    int* ws = (int*)d_ws;
    int*      hist     = ws;                            // BINS
    int*      vcount   = ws + BINS;                     // 1 (+3 pad)
    int*      cursor   = ws + BINS + 4;                 // BINS
    unsigned* packed   = (unsigned*)(ws + 2 * BINS + 4);// N
    int*      perm     = ws + 2 * BINS + 4 + N_VOX;     // N
    int*      vlist    = ws + 2 * BINS + 4 + 2 * N_VOX; // N
    int*      partials = ws + 2 * BINS + 4 + 3 * N_VOX; // 128

    hipMemsetAsync(hist, 0, (BINS + 4) * sizeof(int), stream);  // hist + vcount
    k_hist<<<N_VOX / 256, 256, 0, stream>>>(idx, packed, hist);
    scan_partial<<<BINS / 1024, 256, 0, stream>>>(hist, partials);
    scan_top<<<1, 128, 0, stream>>>(partials);
    scan_final<<<BINS / 1024, 256, 0, stream>>>(hist, partials, cursor);
    k_scatter<<<N_VOX / 256, 256, 0, stream>>>(packed, cursor, perm);
    k_fixup<<<BINS / 256, 256, 0, stream>>>(hist, cursor, packed, perm);
    k_finalize<<<N_VOX / 128, 256, 0, stream>>>(perm, packed, vlist, vcount, out);
    k_valid<<<1024, 512, 0, stream>>>(feats, weight, gamma, beta,
                                      perm, packed, vlist, vcount, out);
}